// Round 1
// baseline (618.651 us; speedup 1.0000x reference)
//
#include <hip/hip_runtime.h>

#define BATCH 4
#define CH    256
#define NTOK  4096
#define DQK   32

typedef __attribute__((ext_vector_type(4))) float  f32x4;
typedef __attribute__((ext_vector_type(8))) __bf16 bf16x8;

// round-to-nearest-even float -> bf16 bits (avoids hip_bf16 header ABI drift)
static __device__ __forceinline__ unsigned short f2bf(float f) {
    unsigned int u = __builtin_bit_cast(unsigned int, f);
    unsigned int r = u + 0x7FFFu + ((u >> 16) & 1u);
    return (unsigned short)(r >> 16);
}

// ---------------------------------------------------------------------------
// Kernel 1: fused 1x1-conv projections  q,k -> [B,N,32] bf16 (token rows),
// v -> [B,C,N] bf16 (channel rows). 64 tokens/block, 5 waves:
// wave0 = q(32)+k(32) rows, waves1-4 = 64 Wv rows each.
// ---------------------------------------------------------------------------
__global__ __launch_bounds__(320)
void qkv_proj(const float* __restrict__ x,
              const float* __restrict__ Wq, const float* __restrict__ bq,
              const float* __restrict__ Wk, const float* __restrict__ bk,
              const float* __restrict__ Wv, const float* __restrict__ bv,
              unsigned short* __restrict__ Qh,
              unsigned short* __restrict__ Kh,
              unsigned short* __restrict__ Vh)
{
    const int t    = threadIdx.x;
    const int lane = t & 63;
    const int g    = t >> 6;                    // wave id 0..4
    const int gt   = blockIdx.x * 64 + lane;    // global token
    const int b    = gt >> 12;                  // / 4096
    const int n    = gt & (NTOK - 1);
    const float* xb = x + (size_t)b * CH * NTOK;

    float acc[64];

    if (g == 0) {
        #pragma unroll
        for (int j = 0; j < 32; ++j) acc[j]      = bq[j];
        #pragma unroll
        for (int j = 0; j < 32; ++j) acc[32 + j] = bk[j];

        for (int c = 0; c < CH; c += 4) {
            float xv0 = xb[(c + 0) * NTOK + n];
            float xv1 = xb[(c + 1) * NTOK + n];
            float xv2 = xb[(c + 2) * NTOK + n];
            float xv3 = xb[(c + 3) * NTOK + n];
            #pragma unroll
            for (int j = 0; j < 32; ++j) {
                const float* wr = Wq + j * CH + c;
                acc[j] += wr[0]*xv0 + wr[1]*xv1 + wr[2]*xv2 + wr[3]*xv3;
            }
            #pragma unroll
            for (int j = 0; j < 32; ++j) {
                const float* wr = Wk + j * CH + c;
                acc[32+j] += wr[0]*xv0 + wr[1]*xv1 + wr[2]*xv2 + wr[3]*xv3;
            }
        }
        size_t base = (size_t)(b * NTOK + n) * DQK;
        #pragma unroll
        for (int j = 0; j < 32; ++j) Qh[base + j] = f2bf(acc[j]);
        #pragma unroll
        for (int j = 0; j < 32; ++j) Kh[base + j] = f2bf(acc[32 + j]);
    } else {
        const int r0 = (g - 1) * 64;
        #pragma unroll
        for (int j = 0; j < 64; ++j) acc[j] = bv[r0 + j];

        for (int c = 0; c < CH; c += 4) {
            float xv0 = xb[(c + 0) * NTOK + n];
            float xv1 = xb[(c + 1) * NTOK + n];
            float xv2 = xb[(c + 2) * NTOK + n];
            float xv3 = xb[(c + 3) * NTOK + n];
            #pragma unroll
            for (int j = 0; j < 64; ++j) {
                const float* wr = Wv + (size_t)(r0 + j) * CH + c;
                acc[j] += wr[0]*xv0 + wr[1]*xv1 + wr[2]*xv2 + wr[3]*xv3;
            }
        }
        #pragma unroll
        for (int j = 0; j < 64; ++j)
            Vh[(size_t)(b * CH + r0 + j) * NTOK + n] = f2bf(acc[j]);
    }
}

// ---------------------------------------------------------------------------
// Kernel 2: flash attention, bf16 MFMA 16x16x32.
// Block = 256 threads = 4 waves; wave handles 16 query rows; 64 queries/block.
// Key chunks of 64. S in C-layout (col=lane&15, row=quad*4+reg); P goes
// C-layout -> LDS -> A-layout (m=lane&15, k=quad*8+j). O acc = 16 c-tiles.
// ---------------------------------------------------------------------------
__global__ __launch_bounds__(256)
void attn(const float* __restrict__ x,
          const unsigned short* __restrict__ Qh,
          const unsigned short* __restrict__ Kh,
          const unsigned short* __restrict__ Vh,
          float* __restrict__ out)
{
    const int t    = threadIdx.x;
    const int wave = t >> 6;
    const int lane = t & 63;
    const int low  = lane & 15;
    const int quad = lane >> 4;
    const int b    = blockIdx.y;
    const int q0   = blockIdx.x * 64;        // block query base
    const int qw   = q0 + wave * 16;         // wave query base

    __shared__ unsigned short plds[4][16 * 72];  // per-wave P, stride 72 bf16
    __shared__ float obuf[64][67];               // transpose buffer (c, q)

    // Q A-fragment: rows m = qw+low, k = quad*8..+7 (16B contiguous)
    const bf16x8 qfrag = *reinterpret_cast<const bf16x8*>(
        Qh + (size_t)(b * NTOK + qw + low) * DQK + quad * 8);

    f32x4 acc[16];
    #pragma unroll
    for (int i = 0; i < 16; ++i) { f32x4 z = {0.f, 0.f, 0.f, 0.f}; acc[i] = z; }
    float m_r[4] = {-3.0e38f, -3.0e38f, -3.0e38f, -3.0e38f};
    float l_r[4] = {0.f, 0.f, 0.f, 0.f};

    const unsigned short* Kb = Kh + (size_t)b * NTOK * DQK;
    const unsigned short* Vb = Vh + (size_t)b * CH * NTOK;
    const float LOG2E = 1.44269504088896f;

    for (int n0 = 0; n0 < NTOK; n0 += 64) {
        // ---- S = Q K^T : 4 key subtiles of 16 ----
        f32x4 S[4];
        #pragma unroll
        for (int kt = 0; kt < 4; ++kt) {
            const bf16x8 kf = *reinterpret_cast<const bf16x8*>(
                Kb + (size_t)(n0 + kt * 16 + low) * DQK + quad * 8);
            f32x4 z = {0.f, 0.f, 0.f, 0.f};
            S[kt] = __builtin_amdgcn_mfma_f32_16x16x32_bf16(qfrag, kf, z, 0, 0, 0);
        }

        // ---- online softmax row stats (row = quad*4+r, cols across 16 lanes)
        float mnew[4], alpha[4];
        bool nochange = true;
        #pragma unroll
        for (int r = 0; r < 4; ++r) {
            float v = fmaxf(fmaxf(S[0][r], S[1][r]), fmaxf(S[2][r], S[3][r]));
            v = fmaxf(v, __shfl_xor(v, 1));
            v = fmaxf(v, __shfl_xor(v, 2));
            v = fmaxf(v, __shfl_xor(v, 4));
            v = fmaxf(v, __shfl_xor(v, 8));
            float mn = fmaxf(m_r[r], v);
            mnew[r]  = mn;
            alpha[r] = __builtin_amdgcn_exp2f((m_r[r] - mn) * LOG2E);
            nochange = nochange && (mn == m_r[r]);
            m_r[r]   = mn;
        }

        // ---- P = exp(S - m), stash bf16 into LDS (C-layout addresses) ----
        #pragma unroll
        for (int kt = 0; kt < 4; ++kt) {
            #pragma unroll
            for (int r = 0; r < 4; ++r) {
                float p = __builtin_amdgcn_exp2f((S[kt][r] - mnew[r]) * LOG2E);
                S[kt][r] = p;
                plds[wave][(quad * 4 + r) * 72 + kt * 16 + low] = f2bf(p);
            }
        }

        // ---- row sums + l update ----
        #pragma unroll
        for (int r = 0; r < 4; ++r) {
            float s = (S[0][r] + S[1][r]) + (S[2][r] + S[3][r]);
            s += __shfl_xor(s, 1);
            s += __shfl_xor(s, 2);
            s += __shfl_xor(s, 4);
            s += __shfl_xor(s, 8);
            l_r[r] = l_r[r] * alpha[r] + s;
        }

        // ---- rescale O (skip if no row max changed anywhere in wave) ----
        if (!__all((int)nochange)) {
            f32x4 a4 = {alpha[0], alpha[1], alpha[2], alpha[3]};
            #pragma unroll
            for (int i = 0; i < 16; ++i) acc[i] *= a4;
        }

        // ---- O += P V^T : A = P (from LDS, A-layout), B = Vh[c][n] ----
        #pragma unroll
        for (int step = 0; step < 2; ++step) {
            const bf16x8 afrag = *reinterpret_cast<const bf16x8*>(
                &plds[wave][low * 72 + step * 32 + quad * 8]);
            #pragma unroll
            for (int ct = 0; ct < 16; ++ct) {
                const bf16x8 vf = *reinterpret_cast<const bf16x8*>(
                    Vb + (size_t)(ct * 16 + low) * NTOK + n0 + step * 32 + quad * 8);
                acc[ct] = __builtin_amdgcn_mfma_f32_16x16x32_bf16(afrag, vf, acc[ct], 0, 0, 0);
            }
        }
    }

    // ---- normalize by softmax denominator ----
    f32x4 inv = {1.f / l_r[0], 1.f / l_r[1], 1.f / l_r[2], 1.f / l_r[3]};
    #pragma unroll
    for (int i = 0; i < 16; ++i) acc[i] *= inv;

    // ---- epilogue: transpose via LDS, fuse residual, coalesced store ----
    const float* xb = x + (size_t)b * CH * NTOK;
    float*       ob = out + (size_t)b * CH * NTOK;
    #pragma unroll
    for (int ci = 0; ci < 4; ++ci) {
        __syncthreads();
        #pragma unroll
        for (int j = 0; j < 4; ++j) {
            const int ct = ci * 4 + j;
            #pragma unroll
            for (int r = 0; r < 4; ++r)
                obuf[j * 16 + low][wave * 16 + quad * 4 + r] = acc[ct][r];
        }
        __syncthreads();
        const int ql = t & 63;
        const int co = t >> 6;
        #pragma unroll
        for (int jj = 0; jj < 16; ++jj) {
            const int cl = co + jj * 4;                  // 0..63
            const int c  = ci * 64 + cl;
            const size_t idx = (size_t)c * NTOK + q0 + ql;
            ob[idx] = xb[idx] + obuf[cl][ql];
        }
    }
}

extern "C" void kernel_launch(void* const* d_in, const int* in_sizes, int n_in,
                              void* d_out, int out_size, void* d_ws, size_t ws_size,
                              hipStream_t stream) {
    const float* x  = (const float*)d_in[0];
    const float* Wq = (const float*)d_in[1];
    const float* bq = (const float*)d_in[2];
    const float* Wk = (const float*)d_in[3];
    const float* bk = (const float*)d_in[4];
    const float* Wv = (const float*)d_in[5];
    const float* bv = (const float*)d_in[6];
    float* out = (float*)d_out;

    unsigned short* Qh = (unsigned short*)d_ws;                // [B,N,32] bf16
    unsigned short* Kh = Qh + (size_t)BATCH * NTOK * DQK;      // [B,N,32] bf16
    unsigned short* Vh = Kh + (size_t)BATCH * NTOK * DQK;      // [B,C,N] bf16

    qkv_proj<<<dim3(256), dim3(320), 0, stream>>>(x, Wq, bq, Wk, bk, Wv, bv,
                                                  Qh, Kh, Vh);
    attn<<<dim3(64, 4), dim3(256), 0, stream>>>(x, Qh, Kh, Vh, out);
}

// Round 2
// 325.243 us; speedup vs baseline: 1.9021x; 1.9021x over previous
//
#include <hip/hip_runtime.h>

#define BATCH 4
#define CH    256
#define NTOK  4096
#define DQK   32

typedef __attribute__((ext_vector_type(4))) float  f32x4;
typedef __attribute__((ext_vector_type(8))) __bf16 bf16x8;
typedef __attribute__((ext_vector_type(8))) unsigned short ushort8;

// round-to-nearest-even float -> bf16 bits
static __device__ __forceinline__ unsigned short f2bf(float f) {
    unsigned int u = __builtin_bit_cast(unsigned int, f);
    unsigned int r = u + 0x7FFFu + ((u >> 16) & 1u);
    return (unsigned short)(r >> 16);
}

// ---------------------------------------------------------------------------
// Kernel 1: projections as (320 rows x 256 K x 16384 tokens) GEMM on VALU.
// Grid (64 token-tiles, 20 row-groups), 256 thr. Thread = 1 token x 16 rows.
// x loads coalesced across lanes; W rows wave-uniform -> s_load.
// ---------------------------------------------------------------------------
__global__ __launch_bounds__(256)
void qkv_proj(const float* __restrict__ x,
              const float* __restrict__ Wq, const float* __restrict__ bq,
              const float* __restrict__ Wk, const float* __restrict__ bk,
              const float* __restrict__ Wv, const float* __restrict__ bv,
              unsigned short* __restrict__ Qh,
              unsigned short* __restrict__ Kh,
              unsigned short* __restrict__ Vh)
{
    const int t     = threadIdx.x;
    const int token = blockIdx.x * 256 + t;      // 0..16383 (256 | 4096: no b straddle)
    const int b     = token >> 12;
    const int n     = token & (NTOK - 1);
    const int rg    = blockIdx.y;                // 0..19

    const float* W; const float* bias; int r0; int which;
    if (rg < 2)      { W = Wq; bias = bq; r0 = rg * 16;       which = 0; }
    else if (rg < 4) { W = Wk; bias = bk; r0 = (rg - 2) * 16; which = 1; }
    else             { W = Wv; bias = bv; r0 = (rg - 4) * 16; which = 2; }

    float acc[16];
    #pragma unroll
    for (int j = 0; j < 16; ++j) acc[j] = bias[r0 + j];

    const float* xp = x + (size_t)b * CH * NTOK + n;
    for (int c = 0; c < CH; c += 4) {
        float xv0 = xp[(size_t)(c + 0) * NTOK];
        float xv1 = xp[(size_t)(c + 1) * NTOK];
        float xv2 = xp[(size_t)(c + 2) * NTOK];
        float xv3 = xp[(size_t)(c + 3) * NTOK];
        #pragma unroll
        for (int j = 0; j < 16; ++j) {
            const float* wr = W + (size_t)(r0 + j) * CH + c;   // wave-uniform
            acc[j] += wr[0]*xv0 + wr[1]*xv1 + wr[2]*xv2 + wr[3]*xv3;
        }
    }

    if (which == 2) {
        #pragma unroll
        for (int j = 0; j < 16; ++j)
            Vh[(size_t)(b * CH + r0 + j) * NTOK + n] = f2bf(acc[j]);
    } else {
        unsigned short* dst = (which ? Kh : Qh) + (size_t)(b * NTOK + n) * DQK + r0;
        ushort8 p0, p1;
        #pragma unroll
        for (int j = 0; j < 8; ++j) { p0[j] = f2bf(acc[j]); p1[j] = f2bf(acc[8 + j]); }
        *reinterpret_cast<ushort8*>(dst)     = p0;
        *reinterpret_cast<ushort8*>(dst + 8) = p1;
    }
}

// ---------------------------------------------------------------------------
// Kernel 2: flash attention. Block = 32 queries, 4 waves; each wave owns a
// quarter of the keys (strided 64-chunks) with private online-softmax state,
// register-blocks 2 query-tiles (V fragment feeds 2 MFMAs). End: merge the 4
// partials via LDS with alpha = e^(m_w - m*), fuse 1/l and residual on store.
// ---------------------------------------------------------------------------
__global__ __launch_bounds__(256, 2)
void attn(const float* __restrict__ x,
          const unsigned short* __restrict__ Qh,
          const unsigned short* __restrict__ Kh,
          const unsigned short* __restrict__ Vh,
          float* __restrict__ out)
{
    const int t    = threadIdx.x;
    const int wave = t >> 6;
    const int lane = t & 63;
    const int low  = lane & 15;
    const int quad = lane >> 4;
    const int b    = blockIdx.y;
    const int q0   = blockIdx.x * 32;

    // smem plan (floats): [0,8320) obuf 4x32x65 | [8320,8448) mbuf | [8448,8576) lbuf
    // plds (ushort, K-loop only) aliases the first 4608 floats.
    __shared__ float smem[4 * 32 * 65 + 4 * 32 * 2];
    unsigned short* plds = (unsigned short*)smem;         // [wave][qt][16][72]
    float* mbuf = smem + 4 * 32 * 65;
    float* lbuf = mbuf + 4 * 32;

    bf16x8 qfrag[2];
    #pragma unroll
    for (int qt = 0; qt < 2; ++qt)
        qfrag[qt] = *reinterpret_cast<const bf16x8*>(
            Qh + (size_t)(b * NTOK + q0 + qt * 16 + low) * DQK + quad * 8);

    f32x4 acc[2][16];
    #pragma unroll
    for (int qt = 0; qt < 2; ++qt)
        #pragma unroll
        for (int i = 0; i < 16; ++i) { f32x4 z = {0.f,0.f,0.f,0.f}; acc[qt][i] = z; }
    float m_r[2][4] = {{-3.0e38f,-3.0e38f,-3.0e38f,-3.0e38f},
                       {-3.0e38f,-3.0e38f,-3.0e38f,-3.0e38f}};
    float l_r[2][4] = {{0.f,0.f,0.f,0.f},{0.f,0.f,0.f,0.f}};

    const unsigned short* Kb = Kh + (size_t)b * NTOK * DQK;
    const unsigned short* Vb = Vh + (size_t)b * CH * NTOK;
    unsigned short* pw = plds + wave * 2 * 1152;          // 16*72 = 1152 per qt
    const float LOG2E = 1.44269504088896f;

    for (int i = 0; i < 16; ++i) {
        const int n0 = (i * 4 + wave) * 64;               // this wave's key chunk

        // ---- S = Q K^T (2 qtiles x 4 ktiles) ----
        f32x4 S[2][4];
        #pragma unroll
        for (int kt = 0; kt < 4; ++kt) {
            bf16x8 kf = *reinterpret_cast<const bf16x8*>(
                Kb + (size_t)(n0 + kt * 16 + low) * DQK + quad * 8);
            f32x4 z = {0.f,0.f,0.f,0.f};
            S[0][kt] = __builtin_amdgcn_mfma_f32_16x16x32_bf16(qfrag[0], kf, z, 0, 0, 0);
            S[1][kt] = __builtin_amdgcn_mfma_f32_16x16x32_bf16(qfrag[1], kf, z, 0, 0, 0);
        }

        // ---- online softmax per qtile ----
        bool nochange = true;
        float alpha[2][4];
        #pragma unroll
        for (int qt = 0; qt < 2; ++qt) {
            float mnew[4];
            #pragma unroll
            for (int r = 0; r < 4; ++r) {
                float v = fmaxf(fmaxf(S[qt][0][r], S[qt][1][r]),
                                fmaxf(S[qt][2][r], S[qt][3][r]));
                v = fmaxf(v, __shfl_xor(v, 1));
                v = fmaxf(v, __shfl_xor(v, 2));
                v = fmaxf(v, __shfl_xor(v, 4));
                v = fmaxf(v, __shfl_xor(v, 8));
                float mn = fmaxf(m_r[qt][r], v);
                mnew[r] = mn;
                alpha[qt][r] = __builtin_amdgcn_exp2f((m_r[qt][r] - mn) * LOG2E);
                nochange = nochange && (mn == m_r[qt][r]);
                m_r[qt][r] = mn;
            }
            #pragma unroll
            for (int kt = 0; kt < 4; ++kt)
                #pragma unroll
                for (int r = 0; r < 4; ++r) {
                    float p = __builtin_amdgcn_exp2f((S[qt][kt][r] - mnew[r]) * LOG2E);
                    S[qt][kt][r] = p;
                    pw[qt * 1152 + (quad * 4 + r) * 72 + kt * 16 + low] = f2bf(p);
                }
            #pragma unroll
            for (int r = 0; r < 4; ++r) {
                float s = (S[qt][0][r] + S[qt][1][r]) + (S[qt][2][r] + S[qt][3][r]);
                s += __shfl_xor(s, 1);
                s += __shfl_xor(s, 2);
                s += __shfl_xor(s, 4);
                s += __shfl_xor(s, 8);
                l_r[qt][r] = l_r[qt][r] * alpha[qt][r] + s;
            }
        }

        if (!__all((int)nochange)) {
            #pragma unroll
            for (int qt = 0; qt < 2; ++qt) {
                f32x4 a4 = {alpha[qt][0], alpha[qt][1], alpha[qt][2], alpha[qt][3]};
                #pragma unroll
                for (int ct = 0; ct < 16; ++ct) acc[qt][ct] *= a4;
            }
        }

        // ---- O += P V^T (V fragment shared across the 2 qtiles) ----
        #pragma unroll
        for (int step = 0; step < 2; ++step) {
            bf16x8 a0 = *reinterpret_cast<const bf16x8*>(
                pw + low * 72 + step * 32 + quad * 8);
            bf16x8 a1 = *reinterpret_cast<const bf16x8*>(
                pw + 1152 + low * 72 + step * 32 + quad * 8);
            #pragma unroll
            for (int ct = 0; ct < 16; ++ct) {
                bf16x8 vf = *reinterpret_cast<const bf16x8*>(
                    Vb + (size_t)(ct * 16 + low) * NTOK + n0 + step * 32 + quad * 8);
                acc[0][ct] = __builtin_amdgcn_mfma_f32_16x16x32_bf16(a0, vf, acc[0][ct], 0, 0, 0);
                acc[1][ct] = __builtin_amdgcn_mfma_f32_16x16x32_bf16(a1, vf, acc[1][ct], 0, 0, 0);
            }
        }
    }

    // ---- publish per-wave m, l ----
    if (low == 0) {
        #pragma unroll
        for (int qt = 0; qt < 2; ++qt)
            #pragma unroll
            for (int r = 0; r < 4; ++r) {
                mbuf[wave * 32 + qt * 16 + quad * 4 + r] = m_r[qt][r];
                lbuf[wave * 32 + qt * 16 + quad * 4 + r] = l_r[qt][r];
            }
    }
    __syncthreads();   // plds dead everywhere; obuf region may now be written

    // ---- merge 4 key-partials, 64 channels per round ----
    const int q  = t & 31;
    const int cb = t >> 5;                                 // 0..7
    for (int rd = 0; rd < 4; ++rd) {
        #pragma unroll
        for (int qt = 0; qt < 2; ++qt)
            #pragma unroll
            for (int j = 0; j < 4; ++j) {
                const int ct = rd * 4 + j;
                #pragma unroll
                for (int r = 0; r < 4; ++r)
                    smem[wave * 2080 + (qt * 16 + quad * 4 + r) * 65 + j * 16 + low]
                        = acc[qt][ct][r];
            }
        __syncthreads();

        float m0 = mbuf[q], m1 = mbuf[32 + q], m2 = mbuf[64 + q], m3 = mbuf[96 + q];
        float ms = fmaxf(fmaxf(m0, m1), fmaxf(m2, m3));
        float a0 = __builtin_amdgcn_exp2f((m0 - ms) * LOG2E);
        float a1 = __builtin_amdgcn_exp2f((m1 - ms) * LOG2E);
        float a2 = __builtin_amdgcn_exp2f((m2 - ms) * LOG2E);
        float a3 = __builtin_amdgcn_exp2f((m3 - ms) * LOG2E);
        float l  = a0 * lbuf[q] + a1 * lbuf[32 + q] + a2 * lbuf[64 + q] + a3 * lbuf[96 + q];
        float invl = 1.0f / l;

        #pragma unroll
        for (int j = 0; j < 8; ++j) {
            const int cl = cb + j * 8;                     // 0..63
            float O = a0 * smem[           q * 65 + cl]
                    + a1 * smem[2080     + q * 65 + cl]
                    + a2 * smem[2 * 2080 + q * 65 + cl]
                    + a3 * smem[3 * 2080 + q * 65 + cl];
            size_t idx = (size_t)(b * CH + rd * 64 + cl) * NTOK + q0 + q;
            out[idx] = x[idx] + O * invl;
        }
        __syncthreads();
    }
}

extern "C" void kernel_launch(void* const* d_in, const int* in_sizes, int n_in,
                              void* d_out, int out_size, void* d_ws, size_t ws_size,
                              hipStream_t stream) {
    const float* x  = (const float*)d_in[0];
    const float* Wq = (const float*)d_in[1];
    const float* bq = (const float*)d_in[2];
    const float* Wk = (const float*)d_in[3];
    const float* bk = (const float*)d_in[4];
    const float* Wv = (const float*)d_in[5];
    const float* bv = (const float*)d_in[6];
    float* out = (float*)d_out;

    unsigned short* Qh = (unsigned short*)d_ws;                // [B,N,32] bf16
    unsigned short* Kh = Qh + (size_t)BATCH * NTOK * DQK;      // [B,N,32] bf16
    unsigned short* Vh = Kh + (size_t)BATCH * NTOK * DQK;      // [B,C,N] bf16

    qkv_proj<<<dim3(64, 20), dim3(256), 0, stream>>>(x, Wq, bq, Wk, bk, Wv, bv,
                                                     Qh, Kh, Vh);
    attn<<<dim3(128, 4), dim3(256), 0, stream>>>(x, Qh, Kh, Vh, out);
}

// Round 3
// 273.168 us; speedup vs baseline: 2.2647x; 1.1906x over previous
//
#include <hip/hip_runtime.h>

#define BATCH 4
#define CH    256
#define NTOK  4096
#define DQK   32

typedef __attribute__((ext_vector_type(4))) float  f32x4;
typedef __attribute__((ext_vector_type(8))) __bf16 bf16x8;
typedef __attribute__((ext_vector_type(2))) unsigned int u32x2;
typedef __attribute__((ext_vector_type(4))) unsigned int u32x4;

// round-to-nearest-even float -> bf16 bits
static __device__ __forceinline__ unsigned short f2bf(float f) {
    unsigned int u = __builtin_bit_cast(unsigned int, f);
    unsigned int r = u + 0x7FFFu + ((u >> 16) & 1u);
    return (unsigned short)(r >> 16);
}
static __device__ __forceinline__ unsigned int pack2(float a, float b) {
    return (unsigned int)f2bf(a) | ((unsigned int)f2bf(b) << 16);
}

// ---------------------------------------------------------------------------
// Kernel 0: convert Wq|Wk|Wv -> Wbf [320 rows][256 c] bf16 (rows 0-31 Q,
// 32-63 K, 64-319 V). 80 blocks x 256 thr x 4 elems.
// ---------------------------------------------------------------------------
__global__ __launch_bounds__(256)
void wconv(const float* __restrict__ Wq, const float* __restrict__ Wk,
           const float* __restrict__ Wv, unsigned short* __restrict__ Wbf)
{
    const int id = (blockIdx.x * 256 + threadIdx.x) * 4;   // 0..81916
    const int r  = id >> 8;
    const int c  = id & 255;
    const float* src = (r < 32) ? (Wq + r * 256 + c)
                     : (r < 64) ? (Wk + (r - 32) * 256 + c)
                                : (Wv + (size_t)(r - 64) * 256 + c);
    float v0 = src[0], v1 = src[1], v2 = src[2], v3 = src[3];
    u32x2 p = {pack2(v0, v1), pack2(v2, v3)};
    *reinterpret_cast<u32x2*>(Wbf + id) = p;
}

// ---------------------------------------------------------------------------
// Kernel 1: QKV projection as bf16 MFMA GEMM. Block = 64 tokens x 320 rows.
// x-tile (64 t x 256 c) staged in LDS once (x read exactly once chip-wide).
// A = X^T (m=token,k=c) from LDS; B = W^T (k=c,n=row) = contiguous Wbf rows.
// D[token][wrow]. Q/K stored as [token][32] bf16; V transposed via LDS to
// [c][token] bf16.
// ---------------------------------------------------------------------------
__global__ __launch_bounds__(256)
void qkv_proj(const float* __restrict__ x,
              const float* __restrict__ pbq, const float* __restrict__ pbk,
              const float* __restrict__ pbv,
              const unsigned short* __restrict__ Wbf,
              unsigned short* __restrict__ Qh,
              unsigned short* __restrict__ Kh,
              unsigned short* __restrict__ Vh)
{
    const int t    = threadIdx.x;
    const int wave = t >> 6;
    const int lane = t & 63;
    const int low  = lane & 15;
    const int quad = lane >> 4;
    const int tok0 = blockIdx.x * 64;           // 64 | 4096 -> single batch
    const int b    = tok0 >> 12;
    const int nl0  = tok0 & (NTOK - 1);

    // LDS: staging x-tile [64 t][264 c-halves] (16896 h) OR epilogue obuf
    // [256 c][68 t-halves] (17408 h). Union.
    __shared__ unsigned short sm[17408];
    unsigned int* smd = (unsigned int*)sm;

    // ---- stage x-tile: thread = (token tl, c-group cg), 64 c's each ----
    {
        const int tl = t & 63, cg = t >> 6;
        const float* xp = x + ((size_t)b * CH + cg * 64) * NTOK + nl0 + tl;
        #pragma unroll
        for (int i = 0; i < 64; i += 8) {
            float v0 = xp[(size_t)(i + 0) * NTOK];
            float v1 = xp[(size_t)(i + 1) * NTOK];
            float v2 = xp[(size_t)(i + 2) * NTOK];
            float v3 = xp[(size_t)(i + 3) * NTOK];
            float v4 = xp[(size_t)(i + 4) * NTOK];
            float v5 = xp[(size_t)(i + 5) * NTOK];
            float v6 = xp[(size_t)(i + 6) * NTOK];
            float v7 = xp[(size_t)(i + 7) * NTOK];
            u32x4 pk = {pack2(v0, v1), pack2(v2, v3), pack2(v4, v5), pack2(v6, v7)};
            *reinterpret_cast<u32x4*>(smd + tl * 132 + cg * 32 + i / 2) = pk;
        }
    }

    // ---- acc init with bias (col = wrow = rt*16+low) ----
    f32x4 acc[20];
    #pragma unroll
    for (int rt = 0; rt < 20; ++rt) {
        float bb = (rt < 2) ? pbq[rt * 16 + low]
                 : (rt < 4) ? pbk[(rt - 2) * 16 + low]
                            : pbv[(rt - 4) * 16 + low];
        f32x4 z = {bb, bb, bb, bb};
        acc[rt] = z;
    }
    __syncthreads();

    // ---- K loop: 8 steps of 32 channels ----
    #pragma unroll
    for (int k0 = 0; k0 < 8; ++k0) {
        const int c0 = k0 * 32;
        const bf16x8 af = *reinterpret_cast<const bf16x8*>(
            sm + (wave * 16 + low) * 264 + c0 + quad * 8);
        #pragma unroll
        for (int rt = 0; rt < 20; ++rt) {
            const bf16x8 bf = *reinterpret_cast<const bf16x8*>(
                Wbf + (size_t)(rt * 16 + low) * 256 + c0 + quad * 8);
            acc[rt] = __builtin_amdgcn_mfma_f32_16x16x32_bf16(af, bf, acc[rt], 0, 0, 0);
        }
    }

    // ---- Q/K epilogue: D[token = tok0+wave*16+quad*4+reg][wrow = rt*16+low]
    #pragma unroll
    for (int rt = 0; rt < 4; ++rt) {
        unsigned short* dst = (rt < 2) ? Qh : Kh;
        const int wr = (rt & 1) * 16 + low;
        #pragma unroll
        for (int reg = 0; reg < 4; ++reg) {
            const int token = tok0 + wave * 16 + quad * 4 + reg;
            dst[(size_t)token * DQK + wr] = f2bf(acc[rt][reg]);
        }
    }

    // ---- V epilogue: transpose via LDS to [c][token] ----
    __syncthreads();   // staging region dead; reuse as obuf [256][68]
    #pragma unroll
    for (int rt = 4; rt < 20; ++rt) {
        const int c = (rt - 4) * 16 + low;
        u32x2 p = {pack2(acc[rt][0], acc[rt][1]), pack2(acc[rt][2], acc[rt][3])};
        *reinterpret_cast<u32x2*>(smd + c * 34 + wave * 8 + quad * 2) = p;
    }
    __syncthreads();
    {
        const int tq = t & 15, c16 = t >> 4;
        #pragma unroll
        for (int ci = 0; ci < 16; ++ci) {
            const int c = ci * 16 + c16;
            u32x2 p = *reinterpret_cast<const u32x2*>(smd + c * 34 + tq * 2);
            *reinterpret_cast<u32x2*>(
                Vh + ((size_t)b * CH + c) * NTOK + nl0 + tq * 4) = p;
        }
    }
}

// ---------------------------------------------------------------------------
// Kernel 2: flash attention, S^T orientation. Block = 32 queries, 4 waves
// key-split (each wave 16 chunks of 64 keys, private online-softmax state).
// S^T = mfma(K, Q^T): D[key][q=low] -> softmax reduces over quads (2 shfl),
// scalar m/l per lane. P^T packed to LDS ([q][key], 4x ds_write_b64,
// conflict-free) and read back as PV B-operand (A = V rows). Final 4-way
// merge via LDS with residual fused on store.
// ---------------------------------------------------------------------------
__global__ __launch_bounds__(256, 2)
void attn(const float* __restrict__ x,
          const unsigned short* __restrict__ Qh,
          const unsigned short* __restrict__ Kh,
          const unsigned short* __restrict__ Vh,
          float* __restrict__ out)
{
    const int t    = threadIdx.x;
    const int wave = t >> 6;
    const int lane = t & 63;
    const int low  = lane & 15;
    const int quad = lane >> 4;
    const int b    = blockIdx.y;
    const int q0   = blockIdx.x * 32;

    // smem (floats): [0,8320) obuf 4x32x65 | [8320,8448) mbuf | [8448,8576) lbuf
    // plds (dwords) aliases obuf: 4 waves x 1152 dwords = 18432 B.
    __shared__ float smem[4 * 2080 + 256];
    unsigned int* plds = (unsigned int*)smem;
    float* mbuf = smem + 8320;
    float* lbuf = mbuf + 128;
    unsigned int* pw = plds + wave * 1152;
    const unsigned short* pwh = (const unsigned short*)pw;

    // Q fragments (B-operand): lane holds Q[q0+qt*16+low][quad*8+j]
    bf16x8 qfrag[2];
    #pragma unroll
    for (int qt = 0; qt < 2; ++qt)
        qfrag[qt] = *reinterpret_cast<const bf16x8*>(
            Qh + (size_t)(b * NTOK + q0 + qt * 16 + low) * DQK + quad * 8);

    f32x4 acc[2][16];
    #pragma unroll
    for (int qt = 0; qt < 2; ++qt)
        #pragma unroll
        for (int i = 0; i < 16; ++i) { f32x4 z = {0.f,0.f,0.f,0.f}; acc[qt][i] = z; }
    float m_s[2] = {-3.0e38f, -3.0e38f};
    float l_s[2] = {0.f, 0.f};

    const unsigned short* Kb = Kh + (size_t)b * NTOK * DQK;
    const unsigned short* Vb = Vh + (size_t)b * CH * NTOK;
    const float LOG2E = 1.44269504088896f;

    // prefetch K fragments for chunk 0 (A-operand: K[key][d])
    bf16x8 kf[4];
    #pragma unroll
    for (int kt = 0; kt < 4; ++kt)
        kf[kt] = *reinterpret_cast<const bf16x8*>(
            Kb + (size_t)(wave * 64 + kt * 16 + low) * DQK + quad * 8);

    for (int i = 0; i < 16; ++i) {
        const int n0 = (i * 4 + wave) * 64;
        const int n1 = ((((i + 1) & 15)) * 4 + wave) * 64;   // wraps; always valid

        // ---- S^T = K Q^T : D[key = kt*16+quad*4+r][q = low] ----
        f32x4 S[2][4];
        #pragma unroll
        for (int kt = 0; kt < 4; ++kt) {
            f32x4 z = {0.f,0.f,0.f,0.f};
            S[0][kt] = __builtin_amdgcn_mfma_f32_16x16x32_bf16(kf[kt], qfrag[0], z, 0, 0, 0);
            S[1][kt] = __builtin_amdgcn_mfma_f32_16x16x32_bf16(kf[kt], qfrag[1], z, 0, 0, 0);
        }

        // ---- prefetch next chunk's K while softmax+PV run ----
        bf16x8 kn[4];
        #pragma unroll
        for (int kt = 0; kt < 4; ++kt)
            kn[kt] = *reinterpret_cast<const bf16x8*>(
                Kb + (size_t)(n1 + kt * 16 + low) * DQK + quad * 8);

        // ---- online softmax (reduce over quads: 2 shuffles) ----
        bool nochange = true;
        float alpha[2];
        #pragma unroll
        for (int qt = 0; qt < 2; ++qt) {
            float mx = S[qt][0][0];
            #pragma unroll
            for (int kt = 0; kt < 4; ++kt)
                #pragma unroll
                for (int r = 0; r < 4; ++r) mx = fmaxf(mx, S[qt][kt][r]);
            mx = fmaxf(mx, __shfl_xor(mx, 16));
            mx = fmaxf(mx, __shfl_xor(mx, 32));
            float mn = fmaxf(m_s[qt], mx);
            alpha[qt] = __builtin_amdgcn_exp2f((m_s[qt] - mn) * LOG2E);
            nochange = nochange && (mn == m_s[qt]);
            m_s[qt] = mn;

            float sum = 0.f;
            unsigned int* pq = pw + qt * 576 + low * 36;
            #pragma unroll
            for (int kt = 0; kt < 4; ++kt) {
                #pragma unroll
                for (int r = 0; r < 4; ++r) {
                    float p = __builtin_amdgcn_exp2f((S[qt][kt][r] - mn) * LOG2E);
                    S[qt][kt][r] = p;
                    sum += p;
                }
                u32x2 w2 = {pack2(S[qt][kt][0], S[qt][kt][1]),
                            pack2(S[qt][kt][2], S[qt][kt][3])};
                *reinterpret_cast<u32x2*>(pq + kt * 8 + quad * 2) = w2;
            }
            sum += __shfl_xor(sum, 16);
            sum += __shfl_xor(sum, 32);
            l_s[qt] = l_s[qt] * alpha[qt] + sum;
        }

        if (!__all((int)nochange)) {
            #pragma unroll
            for (int qt = 0; qt < 2; ++qt)
                #pragma unroll
                for (int ct = 0; ct < 16; ++ct) acc[qt][ct] *= alpha[qt];
        }

        // ---- O += V P^T : A = V rows, B = P^T from LDS ----
        #pragma unroll
        for (int s = 0; s < 2; ++s) {
            const bf16x8 pf0 = *reinterpret_cast<const bf16x8*>(
                pwh + low * 72 + s * 32 + quad * 8);
            const bf16x8 pf1 = *reinterpret_cast<const bf16x8*>(
                pwh + 1152 + low * 72 + s * 32 + quad * 8);
            #pragma unroll
            for (int ct = 0; ct < 16; ++ct) {
                const bf16x8 vf = *reinterpret_cast<const bf16x8*>(
                    Vb + (size_t)(ct * 16 + low) * NTOK + n0 + s * 32 + quad * 8);
                acc[0][ct] = __builtin_amdgcn_mfma_f32_16x16x32_bf16(vf, pf0, acc[0][ct], 0, 0, 0);
                acc[1][ct] = __builtin_amdgcn_mfma_f32_16x16x32_bf16(vf, pf1, acc[1][ct], 0, 0, 0);
            }
        }

        #pragma unroll
        for (int kt = 0; kt < 4; ++kt) kf[kt] = kn[kt];
    }

    // ---- publish per-wave m, l (replicated across quads; quad 0 writes) ----
    if (quad == 0) {
        #pragma unroll
        for (int qt = 0; qt < 2; ++qt) {
            mbuf[wave * 32 + qt * 16 + low] = m_s[qt];
            lbuf[wave * 32 + qt * 16 + low] = l_s[qt];
        }
    }
    __syncthreads();   // all plds use done; obuf region may be written

    // ---- merge 4 key-partials, 64 channels per round ----
    const int q  = t & 31;
    const int cb = t >> 5;                                  // 0..7
    for (int rd = 0; rd < 4; ++rd) {
        // acc value = O[c = ct*16+quad*4+r][q = qt*16+low]
        #pragma unroll
        for (int qt = 0; qt < 2; ++qt)
            #pragma unroll
            for (int j = 0; j < 4; ++j) {
                const int ct = rd * 4 + j;
                #pragma unroll
                for (int r = 0; r < 4; ++r)
                    smem[wave * 2080 + (qt * 16 + low) * 65 + j * 16 + quad * 4 + r]
                        = acc[qt][ct][r];
            }
        __syncthreads();

        float m0 = mbuf[q], m1 = mbuf[32 + q], m2 = mbuf[64 + q], m3 = mbuf[96 + q];
        float ms = fmaxf(fmaxf(m0, m1), fmaxf(m2, m3));
        float a0 = __builtin_amdgcn_exp2f((m0 - ms) * LOG2E);
        float a1 = __builtin_amdgcn_exp2f((m1 - ms) * LOG2E);
        float a2 = __builtin_amdgcn_exp2f((m2 - ms) * LOG2E);
        float a3 = __builtin_amdgcn_exp2f((m3 - ms) * LOG2E);
        float l  = a0 * lbuf[q] + a1 * lbuf[32 + q] + a2 * lbuf[64 + q] + a3 * lbuf[96 + q];
        float invl = 1.0f / l;

        #pragma unroll
        for (int j = 0; j < 8; ++j) {
            const int cl = cb + j * 8;                      // 0..63
            float O = a0 * smem[           q * 65 + cl]
                    + a1 * smem[2080     + q * 65 + cl]
                    + a2 * smem[2 * 2080 + q * 65 + cl]
                    + a3 * smem[3 * 2080 + q * 65 + cl];
            size_t idx = (size_t)(b * CH + rd * 64 + cl) * NTOK + q0 + q;
            out[idx] = x[idx] + O * invl;
        }
        __syncthreads();
    }
}

extern "C" void kernel_launch(void* const* d_in, const int* in_sizes, int n_in,
                              void* d_out, int out_size, void* d_ws, size_t ws_size,
                              hipStream_t stream) {
    const float* x  = (const float*)d_in[0];
    const float* Wq = (const float*)d_in[1];
    const float* bq = (const float*)d_in[2];
    const float* Wk = (const float*)d_in[3];
    const float* bk = (const float*)d_in[4];
    const float* Wv = (const float*)d_in[5];
    const float* bv = (const float*)d_in[6];
    float* out = (float*)d_out;

    unsigned short* Qh  = (unsigned short*)d_ws;                 // [B,N,32] bf16
    unsigned short* Kh  = Qh  + (size_t)BATCH * NTOK * DQK;      // [B,N,32] bf16
    unsigned short* Vh  = Kh  + (size_t)BATCH * NTOK * DQK;      // [B,C,N] bf16
    unsigned short* Wbf = Vh  + (size_t)BATCH * CH * NTOK;       // [320,256] bf16

    wconv<<<dim3(80), dim3(256), 0, stream>>>(Wq, Wk, Wv, Wbf);
    qkv_proj<<<dim3(256), dim3(256), 0, stream>>>(x, bq, bk, bv, Wbf, Qh, Kh, Vh);
    attn<<<dim3(128, 4), dim3(256), 0, stream>>>(x, Qh, Kh, Vh, out);
}